// Round 20
// baseline (36.099 us; speedup 1.0000x reference)
//
#include <hip/hip_runtime.h>

#define MAX_SPIKE 100000.0f

constexpr int BATCH  = 128;
constexpr int NIN    = 1024;
constexpr int MOUT   = 512;
constexpr int NSEG   = 16;            // segments == waves per block
constexpr int SEGLEN = NIN / NSEG;    // 64
constexpr int T      = 1024;          // 16 waves
constexpr int CPB    = 128;           // columns per block (2 ADJACENT per lane)
constexpr int CH     = 4;             // chunk = 4 elements (fits 64-VGPR cap)

typedef unsigned long long u64;

__device__ __forceinline__ float fastrcp(float x) {
#if __has_builtin(__builtin_amdgcn_rcpf)
    return __builtin_amdgcn_rcpf(x);   // v_rcp_f32, 1 ulp
#else
    float r; asm volatile("v_rcp_f32 %0, %1" : "=v"(r) : "v"(x)); return r;
#endif
}

// ================= fused kernel: in-block sort + two-pass scan =============
// r19 (32.2 us, no spill) + two changes with independent diagnostics:
// 1) ABOVE-SKIP: q is monotone-decreasing while above the spike windows and
//    can never re-enter one after dropping below (accept = unique first n
//    with q <= xs[n+1]); so q_end > xs[seg_end]*(1+1e-3) proves the segment
//    holds no accept -> skip. Only crossing segments still screen.
// 2) dwordx2 weight loads at CH=4: buffer set stays 24 floats (fits the
//    64-VGPR cap that r19 proved), load+address issue halves.
__global__ __launch_bounds__(T, 8) void snn_fused_kernel(const float* __restrict__ x,
                                                         const float* __restrict__ w,
                                                         float* __restrict__ out) {
    __shared__ u64 keys[NIN];                        // 8 KB (sort phase)
    __shared__ __align__(16) float xsl[NIN + 8];     // 4.1 KB sorted xs (+sentinel)
    __shared__ __align__(16) int   rol[NIN];         // 4 KB  byte offsets
    __shared__ float4 partsh[NSEG][64];              // 16 KB (pc0,pi0,pc1,pi1)
    __shared__ float  bestsh[NSEG][CPB];             // 8 KB

    const int tid  = threadIdx.x;
    const int b    = blockIdx.x >> 2;
    const int cg   = blockIdx.x & 3;
    const int seg  = tid >> 6;            // wave == segment (uniform work)
    const int lane = tid & 63;
    // lane owns adjacent columns cg*128 + 2*lane, +1 -> one dwordx2 per element
    const unsigned mo8 = (unsigned)(cg * CPB + lane * 2) * 4u;

    // ---------------- phase A: 1-elem/thread hybrid bitonic argsort --------
    // element i == tid. key = (float_bits<<32)|i : x >= 0 so uint order ==
    // float order; index low bits -> distinct keys -> stable argsort.
    {
        u64 e = ((u64)__float_as_uint(x[b * NIN + tid]) << 32) | (unsigned)tid;

        auto CE_SHFL = [&](int k, int j) {           // partner in same wave (j<=32)
            u64 p = __shfl_xor(e, j, 64);
            bool takeMin = (((tid & j) == 0) == ((tid & k) == 0));
            e = ((p < e) == takeMin) ? p : e;
        };
        auto CE_LDS = [&](int k, int j) {            // partner across waves (j>=64)
            keys[tid] = e;
            __syncthreads();
            u64 p = keys[tid ^ j];
            bool takeMin = (((tid & j) == 0) == ((tid & k) == 0));
            e = ((p < e) == takeMin) ? p : e;
            __syncthreads();
        };

        for (int k = 2; k <= 64; k <<= 1)
            for (int j = k >> 1; j >= 1; j >>= 1) CE_SHFL(k, j);
        for (int k = 128; k <= NIN; k <<= 1) {
            for (int j = k >> 1; j >= 64; j >>= 1) CE_LDS(k, j);
            for (int j = 32; j >= 1; j >>= 1) CE_SHFL(k, j);
        }

        xsl[tid] = __uint_as_float((unsigned)(e >> 32));
        rol[tid] = (int)(unsigned)(e & 0xFFFFFFFFull) * (MOUT * 4);  // byte off
        if (tid == 0) xsl[NIN] = MAX_SPIKE;
    }
    __syncthreads();

    // ---------------- phase B: two-pass zero-redundancy scan, 2 cols -------
    const char* wb = (const char*)w;
    float  XA[CH], XB[CH];
    float2 WA[CH], WB[CH];     // direct dwordx2 destinations

// read xs chunk (1x ds_read_b128) + ro (1x b128) + 4 dwordx2 weight loads
#define RDIS(X, W2, c_) { const int cc_ = (c_); \
    float4 a_ = *(const float4*)&xsl[cc_ * 4]; \
    X[0] = a_.x; X[1] = a_.y; X[2] = a_.z; X[3] = a_.w; \
    int4 r_ = *(const int4*)&rol[cc_ * 4]; \
    W2[0] = *(const float2*)(wb + ((unsigned)r_.x + mo8)); \
    W2[1] = *(const float2*)(wb + ((unsigned)r_.y + mo8)); \
    W2[2] = *(const float2*)(wb + ((unsigned)r_.z + mo8)); \
    W2[3] = *(const float2*)(wb + ((unsigned)r_.w + mo8)); }

    const int c0 = seg * (SEGLEN / CH);   // seg*16
    const int c1 = c0 + SEGLEN / CH;      // +16 (even)

    // ---- pass 1: cheap partials over own segment only (both cols)
    float pc0 = 0.0f, pi0 = 0.0f, pc1 = 0.0f, pi1 = 0.0f;
#define CHEAP4(X, W2) { _Pragma("unroll") \
    for (int u = 0; u < CH; ++u) { \
        float xv = X[u]; \
        float w0 = W2[u].x, w1 = W2[u].y; \
        pc0 += w0; pi0 = fmaf(w0, xv, pi0); \
        pc1 += w1; pi1 = fmaf(w1, xv, pi1); } }

    RDIS(XA, WA, c0);
    for (int c = c0; c < c1; c += 2) {
        RDIS(XB, WB, c + 1);
        CHEAP4(XA, WA);
        if (c + 2 < c1) RDIS(XA, WA, c + 2);
        CHEAP4(XB, WB);
    }
#undef CHEAP4

    partsh[seg][lane] = make_float4(pc0, pi0, pc1, pi1);
    __syncthreads();

    // ---- base = ascending sum of earlier segments' partials
    float bc0 = 0.0f, bi0 = 0.0f, bc1 = 0.0f, bi1 = 0.0f;
    for (int t = 0; t < seg; ++t) {
        float4 p = partsh[t][lane];
        bc0 += p.x; bi0 += p.y; bc1 += p.z; bi1 += p.w;
    }

    float best0 = MAX_SPIKE, best1 = MAX_SPIKE;
    {
        const float xn0 = xsl[c0 * 4];               // xs[seg*64] (window bottom)
        const float xn1 = xsl[c1 * 4];               // xs[(seg+1)*64] (top; seg15 -> sentinel)
        const float ec0 = bc0 + pc0, ei0 = bi0 + pi0;
        const float ec1 = bc1 + pc1, ei1 = bi1 + pi1;
        // pre:   wcum < 1 through segment -> no candidate possible.
        // below: base q under window bottom (margin) -> below forever.
        // above: end q over segment-top (margin) -> q stayed above every
        //        window in the segment (monotone while above) -> no accept.
        bool skip0 = (ec0 < 1.0f) ||
                     ((bc0 > 1.0f) && (bi0 < (xn0 * (bc0 - 1.0f)) * (1.0f - 1e-3f))) ||
                     ((ec0 > 1.0f) && (ei0 > (xn1 * (ec0 - 1.0f)) * (1.0f + 1e-3f)));
        bool skip1 = (ec1 < 1.0f) ||
                     ((bc1 > 1.0f) && (bi1 < (xn0 * (bc1 - 1.0f)) * (1.0f - 1e-3f))) ||
                     ((ec1 > 1.0f) && (ei1 > (xn1 * (ec1 - 1.0f)) * (1.0f + 1e-3f)));
        bool skip = (__all((int)(skip0 && skip1)) != 0);

        if (!skip) {
            float wc0 = bc0, wi0 = bi0, wc1 = bc1, wi1 = bi1;
            // Common path: bounds test on wi vs [xv*d, xl*d] (no trans op).
            // Rare branch computes q via v_rcp (1 ulp, validated r12-r19).
            // wc>=1 kept explicitly (kills the xv=0 ^ wi=0 spurious edge).
#define SCREEN4(X, W2, XL4) { _Pragma("unroll") \
    for (int u = 0; u < CH; ++u) { \
        float xv = X[u]; \
        float xl = (u < CH - 1) ? X[u + 1] : (XL4); \
        float w0 = W2[u].x, w1 = W2[u].y; \
        wc0 += w0; wi0 = fmaf(w0, xv, wi0); \
        wc1 += w1; wi1 = fmaf(w1, xv, wi1); \
        float d0 = wc0 - 1.0f; \
        float d1 = wc1 - 1.0f; \
        bool ok0 = (wc0 >= 1.0f) && (wi0 >= xv * d0) && (wi0 <= xl * d0); \
        bool ok1 = (wc1 >= 1.0f) && (wi1 >= xv * d1) && (wi1 <= xl * d1); \
        if (ok0 | ok1) { \
            float q0 = wi0 * fastrcp(fmaxf(d0, 1e-10f)); \
            float q1 = wi1 * fastrcp(fmaxf(d1, 1e-10f)); \
            best0 = ok0 ? fminf(best0, q0) : best0; \
            best1 = ok1 ? fminf(best1, q1) : best1; \
        } } }

            RDIS(XA, WA, c0);
            for (int c = c0; c < c1; c += 2) {
                RDIS(XB, WB, c + 1);
                SCREEN4(XA, WA, XB[0]);
                const bool more = (c + 2 < c1);
                if (more) RDIS(XA, WA, c + 2);
                float xlB = more ? XA[0] : xsl[(c + 2) * 4];  // sentinel-safe
                SCREEN4(XB, WB, xlB);
            }
#undef SCREEN4
        }
    }
#undef RDIS

    bestsh[seg][lane * 2]     = best0;
    bestsh[seg][lane * 2 + 1] = best1;
    __syncthreads();
    if (tid < CPB) {
        float r = bestsh[0][tid];
        #pragma unroll
        for (int s = 1; s < NSEG; ++s) r = fminf(r, bestsh[s][tid]);
        out[b * MOUT + cg * CPB + tid] = r;
    }
}

extern "C" void kernel_launch(void* const* d_in, const int* in_sizes, int n_in,
                              void* d_out, int out_size, void* d_ws, size_t ws_size,
                              hipStream_t stream) {
    (void)in_sizes; (void)n_in; (void)out_size; (void)d_ws; (void)ws_size;
    const float* x = (const float*)d_in[0];
    const float* w = (const float*)d_in[1];
    float* out = (float*)d_out;

    hipLaunchKernelGGL(snn_fused_kernel, dim3(BATCH * (MOUT / CPB)), dim3(T),
                       0, stream, x, w, out);
}

// Round 21
// 31.034 us; speedup vs baseline: 1.1632x; 1.1632x over previous
//
#include <hip/hip_runtime.h>

#define MAX_SPIKE 100000.0f

constexpr int BATCH  = 128;
constexpr int NIN    = 1024;
constexpr int MOUT   = 512;
constexpr int NSEG   = 16;            // segments == waves per block
constexpr int SEGLEN = NIN / NSEG;    // 64
constexpr int T      = 1024;          // 16 waves
constexpr int CPB    = 128;           // columns per block (2 per lane, +256B apart)
constexpr int CH     = 4;             // chunk = 4 elements (fits 64-VGPR cap)

typedef unsigned long long u64;

__device__ __forceinline__ float fastrcp(float x) {
#if __has_builtin(__builtin_amdgcn_rcpf)
    return __builtin_amdgcn_rcpf(x);   // v_rcp_f32, 1 ulp
#else
    float r; asm volatile("v_rcp_f32 %0, %1" : "=v"(r) : "v"(x)); return r;
#endif
}

// ================= fused kernel: in-block sort + two-pass scan =============
// r19 EXACTLY (32.2 us: T=1024, 16 segment-waves, 8 waves/SIMD, 2 strided
// cols/lane, CH=4 scalar loads -- dwordx2 refuted 3x) + ONE change:
// ABOVE-SKIP. q = wi/(wc-1) is monotone-decreasing while above the spike
// windows and never re-enters one after dropping below (accept = unique
// first n with q <= xs[n+1]). So end-of-segment q > xs[seg_end]*(1+1e-3)
// proves the segment holds no accept -> skip its screen loop entirely.
__global__ __launch_bounds__(T, 8) void snn_fused_kernel(const float* __restrict__ x,
                                                         const float* __restrict__ w,
                                                         float* __restrict__ out) {
    __shared__ u64 keys[NIN];                        // 8 KB (sort phase)
    __shared__ __align__(16) float xsl[NIN + 8];     // 4.1 KB sorted xs (+sentinel)
    __shared__ __align__(16) int   rol[NIN];         // 4 KB  byte offsets
    __shared__ float4 partsh[NSEG][64];              // 16 KB (pc0,pi0,pc1,pi1)
    __shared__ float  bestsh[NSEG][CPB];             // 8 KB

    const int tid  = threadIdx.x;
    const int b    = blockIdx.x >> 2;
    const int cg   = blockIdx.x & 3;
    const int seg  = tid >> 6;            // wave == segment (uniform work)
    const int lane = tid & 63;
    const unsigned mo4 = (unsigned)(cg * CPB + lane) * 4u;  // col0; col1 = +256B

    // ---------------- phase A: 1-elem/thread hybrid bitonic argsort --------
    // element i == tid. key = (float_bits<<32)|i : x >= 0 so uint order ==
    // float order; index low bits -> distinct keys -> stable argsort.
    {
        u64 e = ((u64)__float_as_uint(x[b * NIN + tid]) << 32) | (unsigned)tid;

        auto CE_SHFL = [&](int k, int j) {           // partner in same wave (j<=32)
            u64 p = __shfl_xor(e, j, 64);
            bool takeMin = (((tid & j) == 0) == ((tid & k) == 0));
            e = ((p < e) == takeMin) ? p : e;
        };
        auto CE_LDS = [&](int k, int j) {            // partner across waves (j>=64)
            keys[tid] = e;
            __syncthreads();
            u64 p = keys[tid ^ j];
            bool takeMin = (((tid & j) == 0) == ((tid & k) == 0));
            e = ((p < e) == takeMin) ? p : e;
            __syncthreads();
        };

        for (int k = 2; k <= 64; k <<= 1)
            for (int j = k >> 1; j >= 1; j >>= 1) CE_SHFL(k, j);
        for (int k = 128; k <= NIN; k <<= 1) {
            for (int j = k >> 1; j >= 64; j >>= 1) CE_LDS(k, j);
            for (int j = 32; j >= 1; j >>= 1) CE_SHFL(k, j);
        }

        xsl[tid] = __uint_as_float((unsigned)(e >> 32));
        rol[tid] = (int)(unsigned)(e & 0xFFFFFFFFull) * (MOUT * 4);  // byte off
        if (tid == 0) xsl[NIN] = MAX_SPIKE;
    }
    __syncthreads();

    // ---------------- phase B: two-pass zero-redundancy scan, 2 cols -------
    const char* wb = (const char*)w;
    float XA[CH], XB[CH], A0[CH], A1[CH], B0[CH], B1[CH];

// read xs chunk (1x ds_read_b128) + ro (1x b128) + 8 gathered weight loads
#define RDIS(X, V0, V1, c_) { const int cc_ = (c_); \
    float4 a_ = *(const float4*)&xsl[cc_ * 4]; \
    X[0] = a_.x; X[1] = a_.y; X[2] = a_.z; X[3] = a_.w; \
    int4 r_ = *(const int4*)&rol[cc_ * 4]; \
    V0[0] = *(const float*)(wb + ((unsigned)r_.x + mo4)); \
    V1[0] = *(const float*)(wb + ((unsigned)r_.x + mo4 + 256u)); \
    V0[1] = *(const float*)(wb + ((unsigned)r_.y + mo4)); \
    V1[1] = *(const float*)(wb + ((unsigned)r_.y + mo4 + 256u)); \
    V0[2] = *(const float*)(wb + ((unsigned)r_.z + mo4)); \
    V1[2] = *(const float*)(wb + ((unsigned)r_.z + mo4 + 256u)); \
    V0[3] = *(const float*)(wb + ((unsigned)r_.w + mo4)); \
    V1[3] = *(const float*)(wb + ((unsigned)r_.w + mo4 + 256u)); }

    const int c0 = seg * (SEGLEN / CH);   // seg*16
    const int c1 = c0 + SEGLEN / CH;      // +16 (even)

    // ---- pass 1: cheap partials over own segment only (both cols)
    float pc0 = 0.0f, pi0 = 0.0f, pc1 = 0.0f, pi1 = 0.0f;
#define CHEAP4(X, V0, V1) { _Pragma("unroll") \
    for (int u = 0; u < CH; ++u) { \
        float xv = X[u]; \
        float w0 = V0[u], w1 = V1[u]; \
        pc0 += w0; pi0 = fmaf(w0, xv, pi0); \
        pc1 += w1; pi1 = fmaf(w1, xv, pi1); } }

    RDIS(XA, A0, A1, c0);
    for (int c = c0; c < c1; c += 2) {
        RDIS(XB, B0, B1, c + 1);
        CHEAP4(XA, A0, A1);
        if (c + 2 < c1) RDIS(XA, A0, A1, c + 2);
        CHEAP4(XB, B0, B1);
    }
#undef CHEAP4

    partsh[seg][lane] = make_float4(pc0, pi0, pc1, pi1);
    __syncthreads();

    // ---- base = ascending sum of earlier segments' partials
    float bc0 = 0.0f, bi0 = 0.0f, bc1 = 0.0f, bi1 = 0.0f;
    for (int t = 0; t < seg; ++t) {
        float4 p = partsh[t][lane];
        bc0 += p.x; bi0 += p.y; bc1 += p.z; bi1 += p.w;
    }

    float best0 = MAX_SPIKE, best1 = MAX_SPIKE;
    {
        const float xn0 = xsl[c0 * 4];               // xs[seg*64] (window bottom)
        const float xn1 = xsl[c1 * 4];               // xs[(seg+1)*64] (top; seg15 -> sentinel)
        const float ec0 = bc0 + pc0, ei0 = bi0 + pi0;
        const float ec1 = bc1 + pc1, ei1 = bi1 + pi1;
        // pre:   wcum < 1 through segment -> no candidate possible.
        // below: base q under window bottom (margin) -> below forever.
        // above: end q over segment-top (margin) -> q stayed above every
        //        window in the segment (monotone while above) -> no accept.
        bool skip0 = (ec0 < 1.0f) ||
                     ((bc0 > 1.0f) && (bi0 < (xn0 * (bc0 - 1.0f)) * (1.0f - 1e-3f))) ||
                     ((ec0 > 1.0f) && (ei0 > (xn1 * (ec0 - 1.0f)) * (1.0f + 1e-3f)));
        bool skip1 = (ec1 < 1.0f) ||
                     ((bc1 > 1.0f) && (bi1 < (xn0 * (bc1 - 1.0f)) * (1.0f - 1e-3f))) ||
                     ((ec1 > 1.0f) && (ei1 > (xn1 * (ec1 - 1.0f)) * (1.0f + 1e-3f)));
        bool skip = (__all((int)(skip0 && skip1)) != 0);

        if (!skip) {
            float wc0 = bc0, wi0 = bi0, wc1 = bc1, wi1 = bi1;
            // Common path: bounds test on wi vs [xv*d, xl*d] (no trans op).
            // Rare branch computes q via v_rcp (1 ulp, validated r12-r20).
            // wc>=1 kept explicitly (kills the xv=0 ^ wi=0 spurious edge).
#define SCREEN4(X, V0, V1, XL4) { _Pragma("unroll") \
    for (int u = 0; u < CH; ++u) { \
        float xv = X[u]; \
        float xl = (u < CH - 1) ? X[u + 1] : (XL4); \
        float w0 = V0[u], w1 = V1[u]; \
        wc0 += w0; wi0 = fmaf(w0, xv, wi0); \
        wc1 += w1; wi1 = fmaf(w1, xv, wi1); \
        float d0 = wc0 - 1.0f; \
        float d1 = wc1 - 1.0f; \
        bool ok0 = (wc0 >= 1.0f) && (wi0 >= xv * d0) && (wi0 <= xl * d0); \
        bool ok1 = (wc1 >= 1.0f) && (wi1 >= xv * d1) && (wi1 <= xl * d1); \
        if (ok0 | ok1) { \
            float q0 = wi0 * fastrcp(fmaxf(d0, 1e-10f)); \
            float q1 = wi1 * fastrcp(fmaxf(d1, 1e-10f)); \
            best0 = ok0 ? fminf(best0, q0) : best0; \
            best1 = ok1 ? fminf(best1, q1) : best1; \
        } } }

            RDIS(XA, A0, A1, c0);
            for (int c = c0; c < c1; c += 2) {
                RDIS(XB, B0, B1, c + 1);
                SCREEN4(XA, A0, A1, XB[0]);
                const bool more = (c + 2 < c1);
                if (more) RDIS(XA, A0, A1, c + 2);
                float xlB = more ? XA[0] : xsl[(c + 2) * 4];  // sentinel-safe
                SCREEN4(XB, B0, B1, xlB);
            }
#undef SCREEN4
        }
    }
#undef RDIS

    bestsh[seg][lane]      = best0;
    bestsh[seg][lane + 64] = best1;
    __syncthreads();
    if (tid < CPB) {
        float r = bestsh[0][tid];
        #pragma unroll
        for (int s = 1; s < NSEG; ++s) r = fminf(r, bestsh[s][tid]);
        out[b * MOUT + cg * CPB + tid] = r;
    }
}

extern "C" void kernel_launch(void* const* d_in, const int* in_sizes, int n_in,
                              void* d_out, int out_size, void* d_ws, size_t ws_size,
                              hipStream_t stream) {
    (void)in_sizes; (void)n_in; (void)out_size; (void)d_ws; (void)ws_size;
    const float* x = (const float*)d_in[0];
    const float* w = (const float*)d_in[1];
    float* out = (float*)d_out;

    hipLaunchKernelGGL(snn_fused_kernel, dim3(BATCH * (MOUT / CPB)), dim3(T),
                       0, stream, x, w, out);
}

// Round 22
// 31.018 us; speedup vs baseline: 1.1638x; 1.0005x over previous
//
#include <hip/hip_runtime.h>

#define MAX_SPIKE 100000.0f

constexpr int BATCH  = 128;
constexpr int NIN    = 1024;
constexpr int MOUT   = 512;
constexpr int NSEG   = 16;            // segments == waves per block
constexpr int SEGLEN = NIN / NSEG;    // 64
constexpr int T      = 1024;          // 16 waves
constexpr int CPB    = 128;           // columns per block (2 per lane, +256B apart)
constexpr int CH     = 4;             // chunk = 4 elements (fits 64-VGPR cap)

typedef unsigned long long u64;

__device__ __forceinline__ float fastrcp(float x) {
#if __has_builtin(__builtin_amdgcn_rcpf)
    return __builtin_amdgcn_rcpf(x);   // v_rcp_f32, 1 ulp
#else
    float r; asm volatile("v_rcp_f32 %0, %1" : "=v"(r) : "v"(x)); return r;
#endif
}

// ================= fused kernel: in-block sort + two-pass scan =============
// r21 (31.0 us) with ONE change: the sort uses the r4-proven 2-elem/thread
// pair-ownership bitonic (threads 0-511 own i0=wv*128+l, i1=i0+64; j<=32
// shfl, j==64 intra-thread, j>=128 single-barrier LDS pair-exchange).
// Barrier chain 20 -> 9 full-block barriers; LDS-stage compares halved.
// Waves 8-15 idle at sort barriers (their SIMD slots serve the co-resident
// block). Phase B identical to r21 (above/below/pre skips, rcp rare branch).
__global__ __launch_bounds__(T, 8) void snn_fused_kernel(const float* __restrict__ x,
                                                         const float* __restrict__ w,
                                                         float* __restrict__ out) {
    __shared__ u64 keys[NIN];                        // 8 KB (sort phase)
    __shared__ __align__(16) float xsl[NIN + 8];     // 4.1 KB sorted xs (+sentinel)
    __shared__ __align__(16) int   rol[NIN];         // 4 KB  byte offsets
    __shared__ float4 partsh[NSEG][64];              // 16 KB (pc0,pi0,pc1,pi1)
    __shared__ float  bestsh[NSEG][CPB];             // 8 KB

    const int tid  = threadIdx.x;
    const int b    = blockIdx.x >> 2;
    const int cg   = blockIdx.x & 3;
    const int seg  = tid >> 6;            // wave == segment (uniform work)
    const int lane = tid & 63;
    const unsigned mo4 = (unsigned)(cg * CPB + lane) * 4u;  // col0; col1 = +256B

    // ---------------- phase A: 2-elem/thread hybrid bitonic argsort --------
    // Active: threads 0-511. thread (wv,l) owns i0 = wv*128+l, i1 = i0+64.
    // key = (float_bits<<32)|index: x >= 0 so uint order == float order;
    // index low bits -> distinct keys -> deterministic == stable argsort.
    {
        const bool act = (tid < 512);
        const int  wv  = (tid >> 6) & 7;
        const int  l   = lane;
        const int  i0  = wv * 128 + l;    // bit6 == 0 always
        const int  i1  = i0 + 64;

        u64 e0 = 0, e1 = 0;
        if (act) {
            e0 = ((u64)__float_as_uint(x[b * NIN + i0]) << 32) | (unsigned)i0;
            e1 = ((u64)__float_as_uint(x[b * NIN + i1]) << 32) | (unsigned)i1;
        }

        auto CE_SHFL = [&](u64& e, int idx, int k, int j) {
            u64 p = __shfl_xor(e, j, 64);
            bool takeMin = (((l & j) == 0) == ((idx & k) == 0));
            e = ((p < e) == takeMin) ? p : e;
        };
        auto CE_J64 = [&](int k) {
            bool asc = ((i0 & k) == 0);
            bool sw  = asc ? (e0 > e1) : (e0 < e1);
            if (sw) { u64 t = e0; e0 = e1; e1 = t; }
        };

        if (act) {
            for (int k = 2; k <= 64; k <<= 1)
                for (int j = k >> 1; j >= 1; j >>= 1) { CE_SHFL(e0, i0, k, j); CE_SHFL(e1, i1, k, j); }
            CE_J64(128);
            for (int j = 32; j >= 1; j >>= 1) { CE_SHFL(e0, i0, 128, j); CE_SHFL(e1, i1, 128, j); }
        }

        for (int k = 256; k <= NIN; k <<= 1) {
            if (act) { keys[i0] = e0; keys[i1] = e1; }
            __syncthreads();
            for (int j = k >> 1; j >= 128; j >>= 1) {
                if (act) {
                    int idx  = ((tid & ~(j - 1)) << 1) | (tid & (j - 1));
                    int part = idx | j;
                    u64 a = keys[idx], c = keys[part];
                    bool asc = ((idx & k) == 0);
                    if (asc ? (a > c) : (a < c)) { keys[idx] = c; keys[part] = a; }
                }
                __syncthreads();
            }
            if (act) {
                e0 = keys[i0]; e1 = keys[i1];
                CE_J64(k);
                for (int j = 32; j >= 1; j >>= 1) { CE_SHFL(e0, i0, k, j); CE_SHFL(e1, i1, k, j); }
            }
        }

        if (act) {
            xsl[i0] = __uint_as_float((unsigned)(e0 >> 32));
            xsl[i1] = __uint_as_float((unsigned)(e1 >> 32));
            rol[i0] = (int)(unsigned)(e0 & 0xFFFFFFFFull) * (MOUT * 4);  // byte off
            rol[i1] = (int)(unsigned)(e1 & 0xFFFFFFFFull) * (MOUT * 4);
        }
        if (tid == 0) xsl[NIN] = MAX_SPIKE;
    }
    __syncthreads();

    // ---------------- phase B: two-pass zero-redundancy scan, 2 cols -------
    const char* wb = (const char*)w;
    float XA[CH], XB[CH], A0[CH], A1[CH], B0[CH], B1[CH];

// read xs chunk (1x ds_read_b128) + ro (1x b128) + 8 gathered weight loads
#define RDIS(X, V0, V1, c_) { const int cc_ = (c_); \
    float4 a_ = *(const float4*)&xsl[cc_ * 4]; \
    X[0] = a_.x; X[1] = a_.y; X[2] = a_.z; X[3] = a_.w; \
    int4 r_ = *(const int4*)&rol[cc_ * 4]; \
    V0[0] = *(const float*)(wb + ((unsigned)r_.x + mo4)); \
    V1[0] = *(const float*)(wb + ((unsigned)r_.x + mo4 + 256u)); \
    V0[1] = *(const float*)(wb + ((unsigned)r_.y + mo4)); \
    V1[1] = *(const float*)(wb + ((unsigned)r_.y + mo4 + 256u)); \
    V0[2] = *(const float*)(wb + ((unsigned)r_.z + mo4)); \
    V1[2] = *(const float*)(wb + ((unsigned)r_.z + mo4 + 256u)); \
    V0[3] = *(const float*)(wb + ((unsigned)r_.w + mo4)); \
    V1[3] = *(const float*)(wb + ((unsigned)r_.w + mo4 + 256u)); }

    const int c0 = seg * (SEGLEN / CH);   // seg*16
    const int c1 = c0 + SEGLEN / CH;      // +16 (even)

    // ---- pass 1: cheap partials over own segment only (both cols)
    float pc0 = 0.0f, pi0 = 0.0f, pc1 = 0.0f, pi1 = 0.0f;
#define CHEAP4(X, V0, V1) { _Pragma("unroll") \
    for (int u = 0; u < CH; ++u) { \
        float xv = X[u]; \
        float w0 = V0[u], w1 = V1[u]; \
        pc0 += w0; pi0 = fmaf(w0, xv, pi0); \
        pc1 += w1; pi1 = fmaf(w1, xv, pi1); } }

    RDIS(XA, A0, A1, c0);
    for (int c = c0; c < c1; c += 2) {
        RDIS(XB, B0, B1, c + 1);
        CHEAP4(XA, A0, A1);
        if (c + 2 < c1) RDIS(XA, A0, A1, c + 2);
        CHEAP4(XB, B0, B1);
    }
#undef CHEAP4

    partsh[seg][lane] = make_float4(pc0, pi0, pc1, pi1);
    __syncthreads();

    // ---- base = ascending sum of earlier segments' partials
    float bc0 = 0.0f, bi0 = 0.0f, bc1 = 0.0f, bi1 = 0.0f;
    for (int t = 0; t < seg; ++t) {
        float4 p = partsh[t][lane];
        bc0 += p.x; bi0 += p.y; bc1 += p.z; bi1 += p.w;
    }

    float best0 = MAX_SPIKE, best1 = MAX_SPIKE;
    {
        const float xn0 = xsl[c0 * 4];               // xs[seg*64] (window bottom)
        const float xn1 = xsl[c1 * 4];               // xs[(seg+1)*64] (top; seg15 -> sentinel)
        const float ec0 = bc0 + pc0, ei0 = bi0 + pi0;
        const float ec1 = bc1 + pc1, ei1 = bi1 + pi1;
        // pre:   wcum < 1 through segment -> no candidate possible.
        // below: base q under window bottom (margin) -> below forever.
        // above: end q over segment-top (margin) -> q stayed above every
        //        window in the segment (monotone while above) -> no accept.
        bool skip0 = (ec0 < 1.0f) ||
                     ((bc0 > 1.0f) && (bi0 < (xn0 * (bc0 - 1.0f)) * (1.0f - 1e-3f))) ||
                     ((ec0 > 1.0f) && (ei0 > (xn1 * (ec0 - 1.0f)) * (1.0f + 1e-3f)));
        bool skip1 = (ec1 < 1.0f) ||
                     ((bc1 > 1.0f) && (bi1 < (xn0 * (bc1 - 1.0f)) * (1.0f - 1e-3f))) ||
                     ((ec1 > 1.0f) && (ei1 > (xn1 * (ec1 - 1.0f)) * (1.0f + 1e-3f)));
        bool skip = (__all((int)(skip0 && skip1)) != 0);

        if (!skip) {
            float wc0 = bc0, wi0 = bi0, wc1 = bc1, wi1 = bi1;
            // Common path: bounds test on wi vs [xv*d, xl*d] (no trans op).
            // Rare branch computes q via v_rcp (1 ulp, validated r12-r21).
            // wc>=1 kept explicitly (kills the xv=0 ^ wi=0 spurious edge).
#define SCREEN4(X, V0, V1, XL4) { _Pragma("unroll") \
    for (int u = 0; u < CH; ++u) { \
        float xv = X[u]; \
        float xl = (u < CH - 1) ? X[u + 1] : (XL4); \
        float w0 = V0[u], w1 = V1[u]; \
        wc0 += w0; wi0 = fmaf(w0, xv, wi0); \
        wc1 += w1; wi1 = fmaf(w1, xv, wi1); \
        float d0 = wc0 - 1.0f; \
        float d1 = wc1 - 1.0f; \
        bool ok0 = (wc0 >= 1.0f) && (wi0 >= xv * d0) && (wi0 <= xl * d0); \
        bool ok1 = (wc1 >= 1.0f) && (wi1 >= xv * d1) && (wi1 <= xl * d1); \
        if (ok0 | ok1) { \
            float q0 = wi0 * fastrcp(fmaxf(d0, 1e-10f)); \
            float q1 = wi1 * fastrcp(fmaxf(d1, 1e-10f)); \
            best0 = ok0 ? fminf(best0, q0) : best0; \
            best1 = ok1 ? fminf(best1, q1) : best1; \
        } } }

            RDIS(XA, A0, A1, c0);
            for (int c = c0; c < c1; c += 2) {
                RDIS(XB, B0, B1, c + 1);
                SCREEN4(XA, A0, A1, XB[0]);
                const bool more = (c + 2 < c1);
                if (more) RDIS(XA, A0, A1, c + 2);
                float xlB = more ? XA[0] : xsl[(c + 2) * 4];  // sentinel-safe
                SCREEN4(XB, B0, B1, xlB);
            }
#undef SCREEN4
        }
    }
#undef RDIS

    bestsh[seg][lane]      = best0;
    bestsh[seg][lane + 64] = best1;
    __syncthreads();
    if (tid < CPB) {
        float r = bestsh[0][tid];
        #pragma unroll
        for (int s = 1; s < NSEG; ++s) r = fminf(r, bestsh[s][tid]);
        out[b * MOUT + cg * CPB + tid] = r;
    }
}

extern "C" void kernel_launch(void* const* d_in, const int* in_sizes, int n_in,
                              void* d_out, int out_size, void* d_ws, size_t ws_size,
                              hipStream_t stream) {
    (void)in_sizes; (void)n_in; (void)out_size; (void)d_ws; (void)ws_size;
    const float* x = (const float*)d_in[0];
    const float* w = (const float*)d_in[1];
    float* out = (float*)d_out;

    hipLaunchKernelGGL(snn_fused_kernel, dim3(BATCH * (MOUT / CPB)), dim3(T),
                       0, stream, x, w, out);
}